// Round 3
// baseline (53707.660 us; speedup 1.0000x reference)
//
#include <hip/hip_runtime.h>
#include <cstddef>

#define T_LEN 32768
#define HID   300
#define HP    304   // padded row width for x/h buffers
#define HK    320   // padded K for MFMA (10 chunks of 32)
#define KC    10
#define NT    5     // tiles per wave (4 waves x 5 tiles = 20 tiles of 16 rows)
#define IN_D  500
#define OUT_D 100
#define OUTP  104
#define DIST  4     // x prefetch distance (steps)

typedef _Float16 f16x8 __attribute__((ext_vector_type(8)));
typedef float    f32x4 __attribute__((ext_vector_type(4)));

// Static device scratch
__device__ __align__(16) float g_x [(size_t)(T_LEN + DIST) * HP];
__device__ __align__(16) float g_h0[(size_t)T_LEN * HP];
__device__ __align__(16) float g_h1[(size_t)T_LEN * HP];
__device__ __align__(16) float g_wt0[IN_D * HP];
__device__ __align__(16) float g_wt1[HID * HP];
__device__ __align__(16) float g_wtl[HID * OUTP];

// ---------------- transpose + pad: dst[k][j] = (j<J) ? src[j][k] : 0 ----------------
__global__ void k_transpose(const float* __restrict__ src, int J, int K, int JP, int dst_sel)
{
    float* dst = (dst_sel == 0) ? g_wt0 : (dst_sel == 1) ? g_wt1 : g_wtl;
    int idx = blockIdx.x * 256 + threadIdx.x;
    if (idx >= K * JP) return;
    int k = idx / JP, j = idx - k * JP;
    dst[idx] = (j < J) ? src[j * K + k] : 0.f;
}

// ---------------- x = inp @ WT + (b1+b2), 32 rows per block ----------------
__global__ __launch_bounds__(320) void k_gemm_in(const float* __restrict__ in0,
                                                 const float* __restrict__ b1,
                                                 const float* __restrict__ b2,
                                                 int S, int K, int sel)
{
    const float* __restrict__ inp = (sel == 0) ? in0 : g_h0;
    const float* __restrict__ wt  = (sel == 0) ? g_wt0 : g_wt1;
    __shared__ float lds[32 * IN_D];
    const int tid = threadIdx.x;
    const int t0  = blockIdx.x * 32;
    {
        const f32x4* src4 = (const f32x4*)(inp + (size_t)t0 * S);
        f32x4* lds4 = (f32x4*)lds;
        const int n4 = (32 * S) >> 2;
        for (int i = tid; i < n4; i += 320) lds4[i] = src4[i];
    }
    __syncthreads();
    const int j = tid;
    if (j >= HP) return;
    float acc[32];
#pragma unroll
    for (int i = 0; i < 32; i++) acc[i] = 0.f;
#pragma unroll 4
    for (int k = 0; k < K; k++) {
        float w = wt[k * HP + j];
#pragma unroll
        for (int i = 0; i < 32; i++) acc[i] += w * lds[i * S + k];  // uniform addr -> LDS broadcast
    }
    const float bias = (j < HID) ? (b1[j] + b2[j]) : 0.f;
#pragma unroll 4
    for (int i = 0; i < 32; i++) g_x[(size_t)(t0 + i) * HP + j] = acc[i] + bias;
}

// ---------------- out = h1 @ WTl + b_lin, 64 rows per block ----------------
__global__ __launch_bounds__(128) void k_gemm_out(const float* __restrict__ blin,
                                                  float* __restrict__ out)
{
    __shared__ float lds[64 * HP];
    const int tid = threadIdx.x;
    const int t0  = blockIdx.x * 64;
    {
        const f32x4* src4 = (const f32x4*)(g_h1 + (size_t)t0 * HP);
        f32x4* lds4 = (f32x4*)lds;
        for (int i = tid; i < (64 * HP) >> 2; i += 128) lds4[i] = src4[i];
    }
    __syncthreads();
    const int j = tid;
    if (j >= OUTP) return;
    float acc[64];
#pragma unroll
    for (int i = 0; i < 64; i++) acc[i] = 0.f;
#pragma unroll 2
    for (int k = 0; k < HID; k++) {
        float w = g_wtl[k * OUTP + j];
#pragma unroll
        for (int i = 0; i < 64; i++) acc[i] += w * lds[i * HP + k];
    }
    if (j < OUT_D) {
        float b = blin[j];
        for (int i = 0; i < 64; i++) out[(size_t)(t0 + i) * OUT_D + j] = acc[i] + b;
    }
}

// ---------------- serial RNN scan: h_t = tanh(x_t + Whh h_{t-1}) ----------------
__device__ __forceinline__ float fast_tanh(float v)
{
    float e = __expf(2.f * v);
    return 1.f - 2.f * __builtin_amdgcn_rcpf(e + 1.f);
}

// runtime-index-free element select from f32x4 (rule #20: no scratch)
__device__ __forceinline__ float sel4(f32x4 a, bool c1, bool c2)
{
    float v01 = c1 ? a[1] : a[0];
    float v23 = c1 ? a[3] : a[2];
    return c2 ? v23 : v01;
}

// 4 waves, 1 per SIMD. Wave w owns tiles {w, w+4, w+8, w+12, w+16} (16 rows each).
// Per step: 10 broadcast ds_read_b128 of h (vs 80 with 8 waves), 50 MFMA/wave,
// 5 tanh/lane, writers (col<4) publish f16 h to the other LDS buffer + f32 to global.
__global__ __launch_bounds__(256, 1) void k_scan(const float* __restrict__ Whh, int sel)
{
    const float* __restrict__ xin  = g_x;
    float* __restrict__       hout = sel ? g_h1 : g_h0;

    __shared__ __align__(16) _Float16 hlds[2][HK];

    const int tid  = threadIdx.x;
    const int lane = tid & 63;
    const int wave = tid >> 6;       // 0..3
    const int col  = lane & 15;      // MFMA A-row-within-tile / D-col
    const int g    = lane >> 4;      // 0..3 k-group / D row-group
    const int rr   = col & 3;        // acc element this lane finalizes
    const bool c1  = (col & 1) != 0;
    const bool c2  = (col & 2) != 0;
    const bool writer = (col < 4);   // col == rr for writers

    // zero both h LDS buffers (incl. pads)
    for (int i = tid; i < 2 * HK; i += 256) ((_Float16*)hlds)[i] = (_Float16)0.f;

    // per-tile output row this lane finalizes
    int rowv[NT];
#pragma unroll
    for (int i = 0; i < NT; i++) rowv[i] = (i * 4 + wave) * 16 + g * 4 + rr;
    const bool valid4 = (rowv[4] < HP);   // tile 19 rows (304..319) are pure pad

    // W_hh as f16 A-fragments: lane holds row = tile*16 + col, k = kc*32 + g*8 + j.
    // Rows/k >= 300 zeroed so LDS-pad garbage is annihilated.
    f16x8 w[NT][KC];
#pragma unroll
    for (int i = 0; i < NT; i++) {
        const int row = (i * 4 + wave) * 16 + col;
#pragma unroll
        for (int kc = 0; kc < KC; kc++) {
            const int kb = kc * 32 + g * 8;
            f16x8 f;
#pragma unroll
            for (int j = 0; j < 8; j++) {
                const int k = kb + j;
                float wv = (row < HID && k < HID) ? Whh[row * HID + k] : 0.f;
                f[j] = (_Float16)wv;
            }
            w[i][kc] = f;
        }
    }

    __syncthreads();

    // x prefetch: scalar per lane (the element it finalizes), 4 static slots
    float xs[NT][4];
#pragma unroll
    for (int s = 0; s < 4; s++) {
#pragma unroll
        for (int i = 0; i < NT; i++)
            xs[i][s] = (i < 4 || valid4) ? xin[(size_t)s * HP + rowv[i]] : 0.f;
    }

    const f32x4 zero4 = {0.f, 0.f, 0.f, 0.f};

#define STEP(t_, R_, s_) do {                                                          \
        f16x8 bf[KC];                                                                  \
        _Pragma("unroll")                                                              \
        for (int kc = 0; kc < KC; kc++)                                                \
            bf[kc] = *(const f16x8*)&hlds[R_][kc * 32 + g * 8];                        \
        float nx[NT];                                                                  \
        _Pragma("unroll")                                                              \
        for (int i = 0; i < NT; i++)                                                   \
            nx[i] = (i < 4 || valid4)                                                  \
                  ? xin[(size_t)((t_) + DIST) * HP + rowv[i]] : 0.f;                   \
        f32x4 a0[NT], a1[NT];                                                          \
        _Pragma("unroll")                                                              \
        for (int i = 0; i < NT; i++) { a0[i] = zero4; a1[i] = zero4; }                 \
        _Pragma("unroll")                                                              \
        for (int j = 0; j < 5; j++) {                                                  \
            _Pragma("unroll")                                                          \
            for (int i = 0; i < NT; i++)                                               \
                a0[i] = __builtin_amdgcn_mfma_f32_16x16x32_f16(w[i][j], bf[j], a0[i], 0, 0, 0); \
            _Pragma("unroll")                                                          \
            for (int i = 0; i < NT; i++)                                               \
                a1[i] = __builtin_amdgcn_mfma_f32_16x16x32_f16(w[i][j + 5], bf[j + 5], a1[i], 0, 0, 0); \
        }                                                                              \
        _Pragma("unroll")                                                              \
        for (int i = 0; i < NT; i++) {                                                 \
            float sum = sel4(a0[i], c1, c2) + sel4(a1[i], c1, c2);                     \
            float y = fast_tanh(sum + xs[i][s_]);                                      \
            if (writer) {                                                              \
                hlds[1 - (R_)][rowv[i]] = (_Float16)y;                                 \
                if (i < 4 || valid4) hout[(size_t)(t_) * HP + rowv[i]] = y;            \
            }                                                                          \
            xs[i][s_] = nx[i];                                                         \
        }                                                                              \
    } while (0)

// raw barrier: LDS ops drained, vmcnt NOT drained (x prefetch/h stores stay in flight)
#define BAR() do {                                                                     \
        asm volatile("s_waitcnt lgkmcnt(0)" ::: "memory");                             \
        __builtin_amdgcn_sched_barrier(0);                                             \
        __builtin_amdgcn_s_barrier();                                                  \
        __builtin_amdgcn_sched_barrier(0);                                             \
    } while (0)

#pragma unroll 1
    for (int t0 = 0; t0 < T_LEN; t0 += 4) {
        STEP(t0 + 0, 0, 0); BAR();
        STEP(t0 + 1, 1, 1); BAR();
        STEP(t0 + 2, 0, 2); BAR();
        STEP(t0 + 3, 1, 3); BAR();
    }
#undef STEP
#undef BAR
}

extern "C" void kernel_launch(void* const* d_in, const int* in_sizes, int n_in,
                              void* d_out, int out_size, void* d_ws, size_t ws_size,
                              hipStream_t stream)
{
    (void)in_sizes; (void)n_in; (void)d_ws; (void)ws_size; (void)out_size;
    const float* input = (const float*)d_in[0];
    const float* W_ih0 = (const float*)d_in[1];
    const float* W_hh0 = (const float*)d_in[2];
    const float* b_ih0 = (const float*)d_in[3];
    const float* b_hh0 = (const float*)d_in[4];
    const float* W_ih1 = (const float*)d_in[5];
    const float* W_hh1 = (const float*)d_in[6];
    const float* b_ih1 = (const float*)d_in[7];
    const float* b_hh1 = (const float*)d_in[8];
    const float* W_lin = (const float*)d_in[9];
    const float* b_lin = (const float*)d_in[10];
    float* out = (float*)d_out;

    // weight transposes (pad cols zeroed)
    k_transpose<<<dim3((IN_D * HP + 255) / 256), dim3(256), 0, stream>>>(W_ih0, HID, IN_D, HP, 0);
    k_transpose<<<dim3((HID * HP + 255) / 256), dim3(256), 0, stream>>>(W_ih1, HID, HID, HP, 1);
    k_transpose<<<dim3((HID * OUTP + 255) / 256), dim3(256), 0, stream>>>(W_lin, OUT_D, HID, OUTP, 2);

    // x0 = input @ W_ih0^T + (b_ih0 + b_hh0)
    k_gemm_in<<<dim3(T_LEN / 32), dim3(320), 0, stream>>>(input, b_ih0, b_hh0, IN_D, IN_D, 0);
    // layer-0 scan
    k_scan<<<dim3(1), dim3(256), 0, stream>>>(W_hh0, 0);
    // x1 = h0 @ W_ih1^T + (b_ih1 + b_hh1)
    k_gemm_in<<<dim3(T_LEN / 32), dim3(320), 0, stream>>>(nullptr, b_ih1, b_hh1, HP, HID, 1);
    // layer-1 scan
    k_scan<<<dim3(1), dim3(256), 0, stream>>>(W_hh1, 1);
    // head
    k_gemm_out<<<dim3(T_LEN / 64), dim3(128), 0, stream>>>(b_lin, out);
}

// Round 4
// 51652.063 us; speedup vs baseline: 1.0398x; 1.0398x over previous
//
#include <hip/hip_runtime.h>
#include <cstddef>

#define T_LEN 32768
#define HID   300
#define HP    304   // padded row width for x/h buffers
#define HK    320   // padded K for MFMA (10 chunks of 32)
#define KC    10
#define IN_D  500
#define OUT_D 100
#define OUTP  104
#define DIST  8     // x prefetch distance (steps) = slot count

typedef _Float16 f16x8 __attribute__((ext_vector_type(8)));
typedef float    f32x4 __attribute__((ext_vector_type(4)));

// Static device scratch
__device__ __align__(16) float g_x [(size_t)(T_LEN + DIST) * HP];
__device__ __align__(16) float g_h0[(size_t)T_LEN * HP];
__device__ __align__(16) float g_h1[(size_t)T_LEN * HP];
__device__ __align__(16) float g_wt0[IN_D * HP];
__device__ __align__(16) float g_wt1[HID * HP];
__device__ __align__(16) float g_wtl[HID * OUTP];

// ---------------- transpose + pad: dst[k][j] = (j<J) ? src[j][k] : 0 ----------------
__global__ void k_transpose(const float* __restrict__ src, int J, int K, int JP, int dst_sel)
{
    float* dst = (dst_sel == 0) ? g_wt0 : (dst_sel == 1) ? g_wt1 : g_wtl;
    int idx = blockIdx.x * 256 + threadIdx.x;
    if (idx >= K * JP) return;
    int k = idx / JP, j = idx - k * JP;
    dst[idx] = (j < J) ? src[j * K + k] : 0.f;
}

// ---------------- x = inp @ WT + (b1+b2), 32 rows per block ----------------
__global__ __launch_bounds__(320) void k_gemm_in(const float* __restrict__ in0,
                                                 const float* __restrict__ b1,
                                                 const float* __restrict__ b2,
                                                 int S, int K, int sel)
{
    const float* __restrict__ inp = (sel == 0) ? in0 : g_h0;
    const float* __restrict__ wt  = (sel == 0) ? g_wt0 : g_wt1;
    __shared__ float lds[32 * IN_D];
    const int tid = threadIdx.x;
    const int t0  = blockIdx.x * 32;
    {
        const f32x4* src4 = (const f32x4*)(inp + (size_t)t0 * S);
        f32x4* lds4 = (f32x4*)lds;
        const int n4 = (32 * S) >> 2;
        for (int i = tid; i < n4; i += 320) lds4[i] = src4[i];
    }
    __syncthreads();
    const int j = tid;
    if (j >= HP) return;
    float acc[32];
#pragma unroll
    for (int i = 0; i < 32; i++) acc[i] = 0.f;
#pragma unroll 4
    for (int k = 0; k < K; k++) {
        float w = wt[k * HP + j];
#pragma unroll
        for (int i = 0; i < 32; i++) acc[i] += w * lds[i * S + k];  // uniform addr -> LDS broadcast
    }
    const float bias = (j < HID) ? (b1[j] + b2[j]) : 0.f;
#pragma unroll 4
    for (int i = 0; i < 32; i++) g_x[(size_t)(t0 + i) * HP + j] = acc[i] + bias;
}

// ---------------- out = h1 @ WTl + b_lin, 64 rows per block ----------------
__global__ __launch_bounds__(128) void k_gemm_out(const float* __restrict__ blin,
                                                  float* __restrict__ out)
{
    __shared__ float lds[64 * HP];
    const int tid = threadIdx.x;
    const int t0  = blockIdx.x * 64;
    {
        const f32x4* src4 = (const f32x4*)(g_h1 + (size_t)t0 * HP);
        f32x4* lds4 = (f32x4*)lds;
        for (int i = tid; i < (64 * HP) >> 2; i += 128) lds4[i] = src4[i];
    }
    __syncthreads();
    const int j = tid;
    if (j >= OUTP) return;
    float acc[64];
#pragma unroll
    for (int i = 0; i < 64; i++) acc[i] = 0.f;
#pragma unroll 2
    for (int k = 0; k < HID; k++) {
        float w = g_wtl[k * OUTP + j];
#pragma unroll
        for (int i = 0; i < 64; i++) acc[i] += w * lds[i * HP + k];
    }
    if (j < OUT_D) {
        float b = blin[j];
        for (int i = 0; i < 64; i++) out[(size_t)(t0 + i) * OUT_D + j] = acc[i] + b;
    }
}

// ---------------- serial RNN scan: h_t = tanh(x_t + Whh h_{t-1}) ----------------
__device__ __forceinline__ float fast_tanh(float v)
{
    float e = __expf(2.f * v);
    return 1.f - 2.f * __builtin_amdgcn_rcpf(e + 1.f);
}

// runtime-index-free element select from f32x4 (rule #20: no scratch)
__device__ __forceinline__ float sel4(f32x4 a, bool c1, bool c2)
{
    float v01 = c1 ? a[1] : a[0];
    float v23 = c1 ? a[3] : a[2];
    return c2 ? v23 : v01;
}

// 8 waves (2/SIMD). 19 row-tiles of 16: every wave owns {w, w+8}; waves 0-2 also {w+16}.
// Weights pinned in VGPRs via opaque asm def (no remat). x prefetched DIST=8 steps ahead
// into 8 static slots, loads issued at step top, vmcnt never drained in-loop.
__global__ __launch_bounds__(512, 2) void k_scan(const float* __restrict__ Whh, int sel)
{
    const float* __restrict__ xin  = g_x;
    float* __restrict__       hout = sel ? g_h1 : g_h0;

    __shared__ __align__(16) _Float16 hlds[2][HK];

    const int tid  = threadIdx.x;
    const int lane = tid & 63;
    const int wave = tid >> 6;       // 0..7
    const int col  = lane & 15;      // MFMA A-row-within-tile / D-col
    const int g    = lane >> 4;      // 0..3 k-group / D row-group
    const int rr   = col & 3;        // acc element this lane finalizes
    const bool c1  = (col & 1) != 0;
    const bool c2  = (col & 2) != 0;
    const bool writer = (col < 4);

    const int tA = wave, tB = wave + 8, tC = wave + 16;
    const bool hasC = (wave < 3);            // tile 19 (rows 304-319) is pure pad: dropped
    const int rowA = tA * 16 + g * 4 + rr;   // <= 127
    const int rowB = tB * 16 + g * 4 + rr;   // <= 255
    const int rowC = tC * 16 + g * 4 + rr;   // <= 303 (< HP)

    // zero both h LDS buffers (incl. pads)
    for (int i = tid; i < 2 * HK; i += 512) ((_Float16*)hlds)[i] = (_Float16)0.f;

    // W_hh as f16 A-fragments: lane holds row = tile*16 + col, k = kc*32 + g*8 + j.
    // Rows/k >= 300 zeroed so LDS-pad garbage is annihilated.
    auto loadw = [&](int tile, int kc) -> f16x8 {
        const int row = tile * 16 + col;
        const int kb  = kc * 32 + g * 8;
        f16x8 f;
#pragma unroll
        for (int j = 0; j < 8; j++) {
            const int k = kb + j;
            float wv = (row < HID && k < HID) ? Whh[row * HID + k] : 0.f;
            f[j] = (_Float16)wv;
        }
        return f;
    };
    f16x8 wA[KC], wB[KC], wC[KC];
#pragma unroll
    for (int kc = 0; kc < KC; kc++) {
        wA[kc] = loadw(tA, kc);
        wB[kc] = loadw(tB, kc);
        if (hasC) wC[kc] = loadw(tC, kc);
        else {
            f16x8 z;
#pragma unroll
            for (int j = 0; j < 8; j++) z[j] = (_Float16)0.f;
            wC[kc] = z;
        }
    }
    // Pin weight fragments: opaque defs -> compiler cannot rematerialize the loads
#pragma unroll
    for (int kc = 0; kc < KC; kc++) {
        asm volatile("" : "+v"(wA[kc]));
        asm volatile("" : "+v"(wB[kc]));
        asm volatile("" : "+v"(wC[kc]));
    }

    __syncthreads();

    // x prefetch slots: slot s holds x for the next step t with (t & 7) == s
    float xA[DIST], xB[DIST], xC[DIST];
#pragma unroll
    for (int s = 0; s < DIST; s++) {
        xA[s] = xin[(size_t)s * HP + rowA];
        xB[s] = xin[(size_t)s * HP + rowB];
        xC[s] = hasC ? xin[(size_t)s * HP + rowC] : 0.f;
    }

    const f32x4 zero4 = {0.f, 0.f, 0.f, 0.f};

// One timestep. Top: move old x out of slot, issue load for t+8 into the slot
// (consumed 8 steps later -> latency fully hidden). Then 10 broadcast b128 h reads,
// MFMA (2x5 split chains), 1 tanh per lane per tile, writers publish f16->LDS[1-R],
// f32->global.
#define STEP(t_, R_, s_) do {                                                          \
        float xvA = xA[s_], xvB = xB[s_], xvC = xC[s_];                                \
        xA[s_] = xin[(size_t)((t_) + DIST) * HP + rowA];                               \
        xB[s_] = xin[(size_t)((t_) + DIST) * HP + rowB];                               \
        if (hasC) xC[s_] = xin[(size_t)((t_) + DIST) * HP + rowC];                     \
        f16x8 bf[KC];                                                                  \
        _Pragma("unroll")                                                              \
        for (int kc = 0; kc < KC; kc++)                                                \
            bf[kc] = *(const f16x8*)&hlds[R_][kc * 32 + g * 8];                        \
        f32x4 aA0 = zero4, aA1 = zero4, aB0 = zero4, aB1 = zero4;                      \
        f32x4 aC0 = zero4, aC1 = zero4;                                                \
        _Pragma("unroll")                                                              \
        for (int kc = 0; kc < 5; kc++) {                                               \
            aA0 = __builtin_amdgcn_mfma_f32_16x16x32_f16(wA[kc], bf[kc], aA0, 0, 0, 0);\
            aB0 = __builtin_amdgcn_mfma_f32_16x16x32_f16(wB[kc], bf[kc], aB0, 0, 0, 0);\
            if (hasC)                                                                  \
            aC0 = __builtin_amdgcn_mfma_f32_16x16x32_f16(wC[kc], bf[kc], aC0, 0, 0, 0);\
        }                                                                              \
        _Pragma("unroll")                                                              \
        for (int kc = 5; kc < KC; kc++) {                                              \
            aA1 = __builtin_amdgcn_mfma_f32_16x16x32_f16(wA[kc], bf[kc], aA1, 0, 0, 0);\
            aB1 = __builtin_amdgcn_mfma_f32_16x16x32_f16(wB[kc], bf[kc], aB1, 0, 0, 0);\
            if (hasC)                                                                  \
            aC1 = __builtin_amdgcn_mfma_f32_16x16x32_f16(wC[kc], bf[kc], aC1, 0, 0, 0);\
        }                                                                              \
        float sA = sel4(aA0, c1, c2) + sel4(aA1, c1, c2);                              \
        float sB = sel4(aB0, c1, c2) + sel4(aB1, c1, c2);                              \
        float yA = fast_tanh(sA + xvA);                                                \
        float yB = fast_tanh(sB + xvB);                                                \
        float yC = 0.f;                                                                \
        if (hasC) {                                                                    \
            float sC = sel4(aC0, c1, c2) + sel4(aC1, c1, c2);                          \
            yC = fast_tanh(sC + xvC);                                                  \
        }                                                                              \
        if (writer) {                                                                  \
            hlds[1 - (R_)][tA * 16 + g * 4 + col] = (_Float16)yA;                      \
            hlds[1 - (R_)][tB * 16 + g * 4 + col] = (_Float16)yB;                      \
            hout[(size_t)(t_) * HP + rowA] = yA;                                       \
            hout[(size_t)(t_) * HP + rowB] = yB;                                       \
            if (hasC) {                                                                \
                hlds[1 - (R_)][tC * 16 + g * 4 + col] = (_Float16)yC;                  \
                hout[(size_t)(t_) * HP + rowC] = yC;                                   \
            }                                                                          \
        }                                                                              \
    } while (0)

// raw barrier: LDS ops drained, vmcnt NOT drained (x prefetch/h stores stay in flight)
#define BAR() do {                                                                     \
        asm volatile("s_waitcnt lgkmcnt(0)" ::: "memory");                             \
        __builtin_amdgcn_sched_barrier(0);                                             \
        __builtin_amdgcn_s_barrier();                                                  \
        __builtin_amdgcn_sched_barrier(0);                                             \
    } while (0)

#pragma unroll 1
    for (int t0 = 0; t0 < T_LEN; t0 += DIST) {
        STEP(t0 + 0, 0, 0); BAR();
        STEP(t0 + 1, 1, 1); BAR();
        STEP(t0 + 2, 0, 2); BAR();
        STEP(t0 + 3, 1, 3); BAR();
        STEP(t0 + 4, 0, 4); BAR();
        STEP(t0 + 5, 1, 5); BAR();
        STEP(t0 + 6, 0, 6); BAR();
        STEP(t0 + 7, 1, 7); BAR();
    }
#undef STEP
#undef BAR
}

extern "C" void kernel_launch(void* const* d_in, const int* in_sizes, int n_in,
                              void* d_out, int out_size, void* d_ws, size_t ws_size,
                              hipStream_t stream)
{
    (void)in_sizes; (void)n_in; (void)d_ws; (void)ws_size; (void)out_size;
    const float* input = (const float*)d_in[0];
    const float* W_ih0 = (const float*)d_in[1];
    const float* W_hh0 = (const float*)d_in[2];
    const float* b_ih0 = (const float*)d_in[3];
    const float* b_hh0 = (const float*)d_in[4];
    const float* W_ih1 = (const float*)d_in[5];
    const float* W_hh1 = (const float*)d_in[6];
    const float* b_ih1 = (const float*)d_in[7];
    const float* b_hh1 = (const float*)d_in[8];
    const float* W_lin = (const float*)d_in[9];
    const float* b_lin = (const float*)d_in[10];
    float* out = (float*)d_out;

    // weight transposes (pad cols zeroed)
    k_transpose<<<dim3((IN_D * HP + 255) / 256), dim3(256), 0, stream>>>(W_ih0, HID, IN_D, HP, 0);
    k_transpose<<<dim3((HID * HP + 255) / 256), dim3(256), 0, stream>>>(W_ih1, HID, HID, HP, 1);
    k_transpose<<<dim3((HID * OUTP + 255) / 256), dim3(256), 0, stream>>>(W_lin, OUT_D, HID, OUTP, 2);

    // x0 = input @ W_ih0^T + (b_ih0 + b_hh0)
    k_gemm_in<<<dim3(T_LEN / 32), dim3(320), 0, stream>>>(input, b_ih0, b_hh0, IN_D, IN_D, 0);
    // layer-0 scan
    k_scan<<<dim3(1), dim3(512), 0, stream>>>(W_hh0, 0);
    // x1 = h0 @ W_ih1^T + (b_ih1 + b_hh1)
    k_gemm_in<<<dim3(T_LEN / 32), dim3(320), 0, stream>>>(nullptr, b_ih1, b_hh1, HP, HID, 1);
    // layer-1 scan
    k_scan<<<dim3(1), dim3(512), 0, stream>>>(W_hh1, 1);
    // head
    k_gemm_out<<<dim3(T_LEN / 64), dim3(128), 0, stream>>>(b_lin, out);
}

// Round 5
// 24634.344 us; speedup vs baseline: 2.1802x; 2.0968x over previous
//
#include <hip/hip_runtime.h>
#include <cstddef>

#define T_LEN 32768
#define HID   300
#define HP    304   // padded row width for x/h buffers
#define HK    320   // padded K for MFMA (10 chunks of 32)
#define KC    10
#define IN_D  500
#define OUT_D 100
#define OUTP  104
#define DIST  8     // x prefetch distance (steps) = slot count
#define CHUNK 64
#define NCHUNK (T_LEN / CHUNK)

typedef _Float16 f16x8 __attribute__((ext_vector_type(8)));
typedef float    f32x4 __attribute__((ext_vector_type(4)));

// Static device scratch
__device__ __align__(16) float    g_x  [(size_t)(T_LEN + DIST) * HP]; // x0 (layer-0 input proj)
__device__ __align__(16) float    g_x1 [(size_t)(T_LEN + DIST) * HP]; // x1 (layer-1 input proj)
__device__ __align__(16) _Float16 g_h0h[(size_t)T_LEN * HP];          // h0 sequence, f16
__device__ __align__(16) float    g_h1 [(size_t)T_LEN * HP];          // h1 sequence, f32
__device__ __align__(16) float    g_wt0[IN_D * HP];
__device__ __align__(16) float    g_wtl[HID * OUTP];
__device__ int g_flag0;   // chunks of h0 published by scan0
__device__ int g_flag1;   // chunks of x1 published by proj1

// ---------------- reset flags (graph replays!) ----------------
__global__ void k_reset() { g_flag0 = 0; g_flag1 = 0; }

// ---------------- transpose + pad: dst[k][j] = (j<J) ? src[j][k] : 0 ----------------
__global__ void k_transpose(const float* __restrict__ src, int J, int K, int JP, int dst_sel)
{
    float* dst = (dst_sel == 0) ? g_wt0 : g_wtl;
    int idx = blockIdx.x * 256 + threadIdx.x;
    if (idx >= K * JP) return;
    int k = idx / JP, j = idx - k * JP;
    dst[idx] = (j < J) ? src[j * K + k] : 0.f;
}

// ---------------- x0 = input @ W_ih0^T + (b_ih0+b_hh0), 32 rows per block ----------------
__global__ __launch_bounds__(320) void k_gemm_in(const float* __restrict__ inp,
                                                 const float* __restrict__ b1,
                                                 const float* __restrict__ b2)
{
    __shared__ float lds[32 * IN_D];
    const int tid = threadIdx.x;
    const int t0  = blockIdx.x * 32;
    {
        const f32x4* src4 = (const f32x4*)(inp + (size_t)t0 * IN_D);
        f32x4* lds4 = (f32x4*)lds;
        const int n4 = (32 * IN_D) >> 2;
        for (int i = tid; i < n4; i += 320) lds4[i] = src4[i];
    }
    __syncthreads();
    const int j = tid;
    if (j >= HP) return;
    float acc[32];
#pragma unroll
    for (int i = 0; i < 32; i++) acc[i] = 0.f;
#pragma unroll 4
    for (int k = 0; k < IN_D; k++) {
        float w = g_wt0[k * HP + j];
#pragma unroll
        for (int i = 0; i < 32; i++) acc[i] += w * lds[i * IN_D + k];  // uniform addr -> broadcast
    }
    const float bias = (j < HID) ? (b1[j] + b2[j]) : 0.f;
#pragma unroll 4
    for (int i = 0; i < 32; i++) g_x[(size_t)(t0 + i) * HP + j] = acc[i] + bias;
}

// ---------------- out = h1 @ WTl + b_lin, 64 rows per block ----------------
__global__ __launch_bounds__(128) void k_gemm_out(const float* __restrict__ blin,
                                                  float* __restrict__ out)
{
    __shared__ float lds[64 * HP];
    const int tid = threadIdx.x;
    const int t0  = blockIdx.x * 64;
    {
        const f32x4* src4 = (const f32x4*)(g_h1 + (size_t)t0 * HP);
        f32x4* lds4 = (f32x4*)lds;
        for (int i = tid; i < (64 * HP) >> 2; i += 128) lds4[i] = src4[i];
    }
    __syncthreads();
    const int j = tid;
    if (j >= OUTP) return;
    float acc[64];
#pragma unroll
    for (int i = 0; i < 64; i++) acc[i] = 0.f;
#pragma unroll 2
    for (int k = 0; k < HID; k++) {
        float w = g_wtl[k * OUTP + j];
#pragma unroll
        for (int i = 0; i < 64; i++) acc[i] += w * lds[i * HP + k];
    }
    if (j < OUT_D) {
        float b = blin[j];
        for (int i = 0; i < 64; i++) out[(size_t)(t0 + i) * OUT_D + j] = acc[i] + b;
    }
}

// ---------------- helpers ----------------
__device__ __forceinline__ float fast_tanh(float v)
{
    float e = __expf(2.f * v);
    return 1.f - 2.f * __builtin_amdgcn_rcpf(e + 1.f);
}

__device__ __forceinline__ float sel4(f32x4 a, bool c1, bool c2)
{
    float v01 = c1 ? a[1] : a[0];
    float v23 = c1 ? a[3] : a[2];
    return c2 ? v23 : v01;
}

// W row-tile fragment as f16: lane holds row = tile*16+col, k = kc*32+g*8+j; OOB zeroed.
__device__ __forceinline__ f16x8 loadw_frag(const float* __restrict__ W,
                                            int tile, int col, int g, int kc)
{
    const int row = tile * 16 + col;
    const int kb  = kc * 32 + g * 8;
    f16x8 f;
#pragma unroll
    for (int j = 0; j < 8; j++) {
        const int k = kb + j;
        float wv = (row < HID && k < HID) ? W[row * HID + k] : 0.f;
        f[j] = (_Float16)wv;
    }
    return f;
}

// consumer: tid0 spins with agent-scope acquire (buffer_inv), then block-wide barrier
__device__ __forceinline__ void wait_flag(int* f, int target)
{
    if (threadIdx.x == 0) {
        while (__hip_atomic_load(f, __ATOMIC_ACQUIRE, __HIP_MEMORY_SCOPE_AGENT) < target)
            __builtin_amdgcn_s_sleep(8);
    }
    __syncthreads();
}

// producer: __syncthreads drains each wave's vmcnt; release store (wbl2) publishes
__device__ __forceinline__ void publish_flag(int* f, int v)
{
    __syncthreads();
    if (threadIdx.x == 0)
        __hip_atomic_store(f, v, __ATOMIC_RELEASE, __HIP_MEMORY_SCOPE_AGENT);
}

// ---------------- scan role: h_t = tanh(x_t + Whh h_{t-1}) ----------------
// ROLE0=1: layer 0 (publishes g_flag0, writes f16 h0); ROLE0=0: layer 1 (waits on
// g_flag1 with 2-chunk lag, writes f32 h1). 8 waves; 19 row-tiles: {w, w+8, (w<3)+16}.
template<int ROLE0>
__device__ __forceinline__ void scan_role(_Float16 (*hlds)[HK],
                                          const float* __restrict__ Whh,
                                          const float* __restrict__ xin,
                                          _Float16* __restrict__ h16,
                                          float* __restrict__ h32)
{
    const int tid  = threadIdx.x;
    const int lane = tid & 63;
    const int wave = tid >> 6;       // 0..7
    const int col  = lane & 15;
    const int g    = lane >> 4;      // 0..3
    const int rr   = col & 3;
    const bool c1  = (col & 1) != 0;
    const bool c2  = (col & 2) != 0;
    const bool writer = (col < 4);

    const int tA = wave, tB = wave + 8, tC = wave + 16;
    const bool hasC = (wave < 3);            // tile 19 (rows 304-319) is pure pad: dropped
    const int rowA = tA * 16 + g * 4 + rr;
    const int rowB = tB * 16 + g * 4 + rr;
    const int rowC = tC * 16 + g * 4 + rr;   // <= 303

    for (int i = tid; i < 2 * HK; i += 512) ((_Float16*)hlds)[i] = (_Float16)0.f;

    f16x8 wA[KC], wB[KC], wC[KC];
#pragma unroll
    for (int kc = 0; kc < KC; kc++) {
        wA[kc] = loadw_frag(Whh, tA, col, g, kc);
        wB[kc] = loadw_frag(Whh, tB, col, g, kc);
        if (hasC) wC[kc] = loadw_frag(Whh, tC, col, g, kc);
        else {
            f16x8 z;
#pragma unroll
            for (int j = 0; j < 8; j++) z[j] = (_Float16)0.f;
            wC[kc] = z;
        }
    }

    __syncthreads();

    if (!ROLE0) wait_flag(&g_flag1, NCHUNK < 2 ? NCHUNK : 2);  // chunks 0,1 of x1 ready

    // x prefetch slots: slot s holds x for the next step t with (t & 7) == s
    float xA[DIST], xB[DIST], xC[DIST];
#pragma unroll
    for (int s = 0; s < DIST; s++) {
        xA[s] = xin[(size_t)s * HP + rowA];
        xB[s] = xin[(size_t)s * HP + rowB];
        xC[s] = hasC ? xin[(size_t)s * HP + rowC] : 0.f;
    }

    const f32x4 zero4 = {0.f, 0.f, 0.f, 0.f};

#define STEP(t_, R_, s_) do {                                                          \
        float xvA = xA[s_], xvB = xB[s_], xvC = xC[s_];                                \
        xA[s_] = xin[(size_t)((t_) + DIST) * HP + rowA];                               \
        xB[s_] = xin[(size_t)((t_) + DIST) * HP + rowB];                               \
        if (hasC) xC[s_] = xin[(size_t)((t_) + DIST) * HP + rowC];                     \
        f16x8 bf[KC];                                                                  \
        _Pragma("unroll")                                                              \
        for (int kc = 0; kc < KC; kc++)                                                \
            bf[kc] = *(const f16x8*)&hlds[R_][kc * 32 + g * 8];                        \
        f32x4 aA0 = zero4, aA1 = zero4, aB0 = zero4, aB1 = zero4;                      \
        f32x4 aC0 = zero4, aC1 = zero4;                                                \
        _Pragma("unroll")                                                              \
        for (int kc = 0; kc < 5; kc++) {                                               \
            aA0 = __builtin_amdgcn_mfma_f32_16x16x32_f16(wA[kc], bf[kc], aA0, 0, 0, 0);\
            aB0 = __builtin_amdgcn_mfma_f32_16x16x32_f16(wB[kc], bf[kc], aB0, 0, 0, 0);\
            if (hasC)                                                                  \
            aC0 = __builtin_amdgcn_mfma_f32_16x16x32_f16(wC[kc], bf[kc], aC0, 0, 0, 0);\
        }                                                                              \
        _Pragma("unroll")                                                              \
        for (int kc = 5; kc < KC; kc++) {                                              \
            aA1 = __builtin_amdgcn_mfma_f32_16x16x32_f16(wA[kc], bf[kc], aA1, 0, 0, 0);\
            aB1 = __builtin_amdgcn_mfma_f32_16x16x32_f16(wB[kc], bf[kc], aB1, 0, 0, 0);\
            if (hasC)                                                                  \
            aC1 = __builtin_amdgcn_mfma_f32_16x16x32_f16(wC[kc], bf[kc], aC1, 0, 0, 0);\
        }                                                                              \
        float sA = sel4(aA0, c1, c2) + sel4(aA1, c1, c2);                              \
        float sB = sel4(aB0, c1, c2) + sel4(aB1, c1, c2);                              \
        float yA = fast_tanh(sA + xvA);                                                \
        float yB = fast_tanh(sB + xvB);                                                \
        float yC = 0.f;                                                                \
        if (hasC) {                                                                    \
            float sC = sel4(aC0, c1, c2) + sel4(aC1, c1, c2);                          \
            yC = fast_tanh(sC + xvC);                                                  \
        }                                                                              \
        if (writer) {                                                                  \
            _Float16 hA = (_Float16)yA, hB = (_Float16)yB, hC = (_Float16)yC;          \
            hlds[1 - (R_)][tA * 16 + g * 4 + col] = hA;                                \
            hlds[1 - (R_)][tB * 16 + g * 4 + col] = hB;                                \
            if (hasC) hlds[1 - (R_)][tC * 16 + g * 4 + col] = hC;                      \
            if (ROLE0) {                                                               \
                h16[(size_t)(t_) * HP + rowA] = hA;                                    \
                h16[(size_t)(t_) * HP + rowB] = hB;                                    \
                if (hasC) h16[(size_t)(t_) * HP + rowC] = hC;                          \
            } else {                                                                   \
                h32[(size_t)(t_) * HP + rowA] = yA;                                    \
                h32[(size_t)(t_) * HP + rowB] = yB;                                    \
                if (hasC) h32[(size_t)(t_) * HP + rowC] = yC;                          \
            }                                                                          \
        }                                                                              \
    } while (0)

#define BAR() do {                                                                     \
        asm volatile("s_waitcnt lgkmcnt(0)" ::: "memory");                             \
        __builtin_amdgcn_sched_barrier(0);                                             \
        __builtin_amdgcn_s_barrier();                                                  \
        __builtin_amdgcn_sched_barrier(0);                                             \
    } while (0)

#pragma unroll 1
    for (int c = 0; c < NCHUNK; ++c) {
        if (!ROLE0 && c > 0) {
            int tgt = (c + 2) < NCHUNK ? (c + 2) : NCHUNK;
            wait_flag(&g_flag1, tgt);
        }
#pragma unroll 1
        for (int tt = 0; tt < CHUNK; tt += DIST) {
            const int tb = c * CHUNK + tt;
            STEP(tb + 0, 0, 0); BAR();
            STEP(tb + 1, 1, 1); BAR();
            STEP(tb + 2, 0, 2); BAR();
            STEP(tb + 3, 1, 3); BAR();
            STEP(tb + 4, 0, 4); BAR();
            STEP(tb + 5, 1, 5); BAR();
            STEP(tb + 6, 0, 6); BAR();
            STEP(tb + 7, 1, 7); BAR();
        }
        if (ROLE0) publish_flag(&g_flag0, c + 1);
    }
#undef STEP
#undef BAR
}

// ---------------- proj role: x1[t] = W_ih1 h0[t] + (b_ih1+b_hh1), chunked ----------------
__device__ __forceinline__ void proj_role(const float* __restrict__ Wih,
                                          const float* __restrict__ b1,
                                          const float* __restrict__ b2)
{
    const int tid  = threadIdx.x;
    const int lane = tid & 63;
    const int wave = tid >> 6;
    const int col  = lane & 15;      // timestep-within-16-group (B col / D col)
    const int g    = lane >> 4;      // k-subgroup / D row-group

    const int tA = wave, tB = wave + 8, tC = wave + 16;
    const bool hasC = (wave < 3);

    f16x8 wA[KC], wB[KC], wC[KC];
#pragma unroll
    for (int kc = 0; kc < KC; kc++) {
        wA[kc] = loadw_frag(Wih, tA, col, g, kc);
        wB[kc] = loadw_frag(Wih, tB, col, g, kc);
        if (hasC) wC[kc] = loadw_frag(Wih, tC, col, g, kc);
        else {
            f16x8 z;
#pragma unroll
            for (int j = 0; j < 8; j++) z[j] = (_Float16)0.f;
            wC[kc] = z;
        }
    }
    // bias vectors for this lane's 4 output rows per tile (zero for j>=HID)
    f32x4 bA, bB, bC;
#pragma unroll
    for (int e = 0; e < 4; e++) {
        int jA = tA * 16 + g * 4 + e, jB = tB * 16 + g * 4 + e, jC = tC * 16 + g * 4 + e;
        bA[e] = (jA < HID) ? b1[jA] + b2[jA] : 0.f;
        bB[e] = (jB < HID) ? b1[jB] + b2[jB] : 0.f;
        bC[e] = (hasC && jC < HID) ? b1[jC] + b2[jC] : 0.f;
    }

    const f32x4 zero4 = {0.f, 0.f, 0.f, 0.f};

#pragma unroll 1
    for (int c = 0; c < NCHUNK; ++c) {
        wait_flag(&g_flag0, c + 1);
        const int tbase = c * CHUNK;
#pragma unroll
        for (int tg = 0; tg < 4; ++tg) {
            const int t = tbase + tg * 16 + col;
            f16x8 bf[KC];
#pragma unroll
            for (int kc = 0; kc < KC; ++kc)
                bf[kc] = *(const f16x8*)&g_h0h[(size_t)t * HP + kc * 32 + g * 8];
            f32x4 aA = zero4, aB = zero4, aC = zero4;
#pragma unroll
            for (int kc = 0; kc < KC; ++kc) {
                aA = __builtin_amdgcn_mfma_f32_16x16x32_f16(wA[kc], bf[kc], aA, 0, 0, 0);
                aB = __builtin_amdgcn_mfma_f32_16x16x32_f16(wB[kc], bf[kc], aB, 0, 0, 0);
                if (hasC)
                aC = __builtin_amdgcn_mfma_f32_16x16x32_f16(wC[kc], bf[kc], aC, 0, 0, 0);
            }
            // D: col=lane&15 -> t, row=g*4+e -> j within tile; f32x4 store per tile
            *(f32x4*)&g_x1[(size_t)t * HP + tA * 16 + g * 4] = aA + bA;
            *(f32x4*)&g_x1[(size_t)t * HP + tB * 16 + g * 4] = aB + bB;
            if (hasC)
            *(f32x4*)&g_x1[(size_t)t * HP + tC * 16 + g * 4] = aC + bC;
        }
        publish_flag(&g_flag1, c + 1);
    }
}

// ---------------- fused pipeline: block0=scan0, block1=proj1, block2=scan1 ----------------
__global__ __launch_bounds__(512, 2) void k_pipeline(const float* __restrict__ W_hh0,
                                                     const float* __restrict__ W_ih1,
                                                     const float* __restrict__ b_ih1,
                                                     const float* __restrict__ b_hh1,
                                                     const float* __restrict__ W_hh1)
{
    __shared__ __align__(16) _Float16 hlds[2][HK];
    if (blockIdx.x == 0)
        scan_role<1>(hlds, W_hh0, g_x, g_h0h, nullptr);
    else if (blockIdx.x == 1)
        proj_role(W_ih1, b_ih1, b_hh1);
    else
        scan_role<0>(hlds, W_hh1, g_x1, nullptr, g_h1);
}

extern "C" void kernel_launch(void* const* d_in, const int* in_sizes, int n_in,
                              void* d_out, int out_size, void* d_ws, size_t ws_size,
                              hipStream_t stream)
{
    (void)in_sizes; (void)n_in; (void)d_ws; (void)ws_size; (void)out_size;
    const float* input = (const float*)d_in[0];
    const float* W_ih0 = (const float*)d_in[1];
    const float* W_hh0 = (const float*)d_in[2];
    const float* b_ih0 = (const float*)d_in[3];
    const float* b_hh0 = (const float*)d_in[4];
    const float* W_ih1 = (const float*)d_in[5];
    const float* W_hh1 = (const float*)d_in[6];
    const float* b_ih1 = (const float*)d_in[7];
    const float* b_hh1 = (const float*)d_in[8];
    const float* W_lin = (const float*)d_in[9];
    const float* b_lin = (const float*)d_in[10];
    float* out = (float*)d_out;

    k_reset<<<dim3(1), dim3(1), 0, stream>>>();
    k_transpose<<<dim3((IN_D * HP + 255) / 256), dim3(256), 0, stream>>>(W_ih0, HID, IN_D, HP, 0);
    k_transpose<<<dim3((HID * OUTP + 255) / 256), dim3(256), 0, stream>>>(W_lin, OUT_D, HID, OUTP, 2);

    // x0 = input @ W_ih0^T + (b_ih0 + b_hh0)
    k_gemm_in<<<dim3(T_LEN / 32), dim3(320), 0, stream>>>(input, b_ih0, b_hh0);

    // fused scan0 | proj1 | scan1 pipeline (3 co-resident workgroups)
    k_pipeline<<<dim3(3), dim3(512), 0, stream>>>(W_hh0, W_ih1, b_ih1, b_hh1, W_hh1);

    // head
    k_gemm_out<<<dim3(T_LEN / 64), dim3(128), 0, stream>>>(b_lin, out);
}

// Round 6
// 24416.869 us; speedup vs baseline: 2.1996x; 1.0089x over previous
//
#include <hip/hip_runtime.h>
#include <cstddef>

#define T_LEN 32768
#define HID   300
#define HP    304   // padded row width for x/h buffers
#define HK    320   // padded K for MFMA (10 chunks of 32)
#define KC    10
#define IN_D  500
#define OUT_D 100
#define OUTP  104
#define DIST  8     // x prefetch distance (steps) = slot count
#define CHUNK 64
#define NCHUNK (T_LEN / CHUNK)

typedef _Float16 f16x8 __attribute__((ext_vector_type(8)));
typedef float    f32x4 __attribute__((ext_vector_type(4)));

// Static device scratch
__device__ __align__(16) float    g_x  [(size_t)(T_LEN + DIST) * HP]; // x0 (layer-0 input proj)
__device__ __align__(16) float    g_x1 [(size_t)(T_LEN + DIST) * HP]; // x1 (layer-1 input proj)
__device__ __align__(16) _Float16 g_h0h[(size_t)T_LEN * HP];          // h0 sequence, f16
__device__ __align__(16) float    g_h1 [(size_t)T_LEN * HP];          // h1 sequence, f32
__device__ __align__(16) float    g_wt0[IN_D * HP];
__device__ __align__(16) float    g_wtl[HID * OUTP];
__device__ int g_flag0;   // chunks of h0 published by scan0
__device__ int g_flag1;   // chunks of x1 published by proj1

// ---------------- reset flags (graph replays!) ----------------
__global__ void k_reset() { g_flag0 = 0; g_flag1 = 0; }

// ---------------- transpose + pad: dst[k][j] = (j<J) ? src[j][k] : 0 ----------------
__global__ void k_transpose(const float* __restrict__ src, int J, int K, int JP, int dst_sel)
{
    float* dst = (dst_sel == 0) ? g_wt0 : g_wtl;
    int idx = blockIdx.x * 256 + threadIdx.x;
    if (idx >= K * JP) return;
    int k = idx / JP, j = idx - k * JP;
    dst[idx] = (j < J) ? src[j * K + k] : 0.f;
}

// ---------------- x0 = input @ W_ih0^T + (b_ih0+b_hh0), 32 rows per block ----------------
__global__ __launch_bounds__(320) void k_gemm_in(const float* __restrict__ inp,
                                                 const float* __restrict__ b1,
                                                 const float* __restrict__ b2)
{
    __shared__ float lds[32 * IN_D];
    const int tid = threadIdx.x;
    const int t0  = blockIdx.x * 32;
    {
        const f32x4* src4 = (const f32x4*)(inp + (size_t)t0 * IN_D);
        f32x4* lds4 = (f32x4*)lds;
        const int n4 = (32 * IN_D) >> 2;
        for (int i = tid; i < n4; i += 320) lds4[i] = src4[i];
    }
    __syncthreads();
    const int j = tid;
    if (j >= HP) return;
    float acc[32];
#pragma unroll
    for (int i = 0; i < 32; i++) acc[i] = 0.f;
#pragma unroll 4
    for (int k = 0; k < IN_D; k++) {
        float w = g_wt0[k * HP + j];
#pragma unroll
        for (int i = 0; i < 32; i++) acc[i] += w * lds[i * IN_D + k];  // uniform addr -> broadcast
    }
    const float bias = (j < HID) ? (b1[j] + b2[j]) : 0.f;
#pragma unroll 4
    for (int i = 0; i < 32; i++) g_x[(size_t)(t0 + i) * HP + j] = acc[i] + bias;
}

// ---------------- out = h1 @ WTl + b_lin, 64 rows per block ----------------
__global__ __launch_bounds__(128) void k_gemm_out(const float* __restrict__ blin,
                                                  float* __restrict__ out)
{
    __shared__ float lds[64 * HP];
    const int tid = threadIdx.x;
    const int t0  = blockIdx.x * 64;
    {
        const f32x4* src4 = (const f32x4*)(g_h1 + (size_t)t0 * HP);
        f32x4* lds4 = (f32x4*)lds;
        for (int i = tid; i < (64 * HP) >> 2; i += 128) lds4[i] = src4[i];
    }
    __syncthreads();
    const int j = tid;
    if (j >= OUTP) return;
    float acc[64];
#pragma unroll
    for (int i = 0; i < 64; i++) acc[i] = 0.f;
#pragma unroll 2
    for (int k = 0; k < HID; k++) {
        float w = g_wtl[k * OUTP + j];
#pragma unroll
        for (int i = 0; i < 64; i++) acc[i] += w * lds[i * HP + k];
    }
    if (j < OUT_D) {
        float b = blin[j];
        for (int i = 0; i < 64; i++) out[(size_t)(t0 + i) * OUT_D + j] = acc[i] + b;
    }
}

// ---------------- helpers ----------------
__device__ __forceinline__ float fast_tanh(float v)
{
    float e = __expf(2.f * v);
    return 1.f - 2.f * __builtin_amdgcn_rcpf(e + 1.f);
}

__device__ __forceinline__ float sel4(f32x4 a, bool c1, bool c2)
{
    float v01 = c1 ? a[1] : a[0];
    float v23 = c1 ? a[3] : a[2];
    return c2 ? v23 : v01;
}

// W row-tile fragment as f16: lane holds row = tile*16+col, k = kc*32+g*8+j; OOB zeroed.
__device__ __forceinline__ f16x8 loadw_frag(const float* __restrict__ W,
                                            int tile, int col, int g, int kc)
{
    const int row = tile * 16 + col;
    const int kb  = kc * 32 + g * 8;
    f16x8 f;
#pragma unroll
    for (int j = 0; j < 8; j++) {
        const int k = kb + j;
        float wv = (row < HID && k < HID) ? W[row * HID + k] : 0.f;
        f[j] = (_Float16)wv;
    }
    return f;
}

// consumer: tid0 spins with agent-scope acquire (buffer_inv), then block-wide barrier
__device__ __forceinline__ void wait_flag(int* f, int target)
{
    if (threadIdx.x == 0) {
        while (__hip_atomic_load(f, __ATOMIC_ACQUIRE, __HIP_MEMORY_SCOPE_AGENT) < target)
            __builtin_amdgcn_s_sleep(8);
    }
    __syncthreads();
}

// producer: __syncthreads drains each wave's vmcnt; release store (wbl2) publishes
__device__ __forceinline__ void publish_flag(int* f, int v)
{
    __syncthreads();
    if (threadIdx.x == 0)
        __hip_atomic_store(f, v, __ATOMIC_RELEASE, __HIP_MEMORY_SCOPE_AGENT);
}

// ---------------- scan role: h_t = tanh(x_t + Whh h_{t-1}) ----------------
// ROLE0=1: layer 0 (publishes g_flag0, writes f16 h0); ROLE0=0: layer 1 (waits on
// g_flag1 with 2-chunk lag, writes f32 h1). 8 waves; 19 row-tiles: {w, w+8, (w<3)+16}.
template<int ROLE0>
__device__ __forceinline__ void scan_role(_Float16 (*hlds)[HK],
                                          const float* __restrict__ Whh,
                                          const float* __restrict__ xin,
                                          _Float16* __restrict__ h16,
                                          float* __restrict__ h32)
{
    const int tid  = threadIdx.x;
    const int lane = tid & 63;
    const int wave = tid >> 6;       // 0..7
    const int col  = lane & 15;
    const int g    = lane >> 4;      // 0..3
    const int rr   = col & 3;
    const bool c1  = (col & 1) != 0;
    const bool c2  = (col & 2) != 0;
    const bool writer = (col < 4);

    const int tA = wave, tB = wave + 8, tC = wave + 16;
    const bool hasC = (wave < 3);            // tile 19 (rows 304-319) is pure pad: dropped
    const int rowA = tA * 16 + g * 4 + rr;
    const int rowB = tB * 16 + g * 4 + rr;
    const int rowC = tC * 16 + g * 4 + rr;   // <= 303

    for (int i = tid; i < 2 * HK; i += 512) ((_Float16*)hlds)[i] = (_Float16)0.f;

    f16x8 wA[KC], wB[KC], wC[KC];
#pragma unroll
    for (int kc = 0; kc < KC; kc++) {
        wA[kc] = loadw_frag(Whh, tA, col, g, kc);
        wB[kc] = loadw_frag(Whh, tB, col, g, kc);
        if (hasC) wC[kc] = loadw_frag(Whh, tC, col, g, kc);
        else {
            f16x8 z;
#pragma unroll
            for (int j = 0; j < 8; j++) z[j] = (_Float16)0.f;
            wC[kc] = z;
        }
    }

    __syncthreads();

    if (!ROLE0) wait_flag(&g_flag1, NCHUNK < 2 ? NCHUNK : 2);  // chunks 0,1 of x1 ready

    // x prefetch slots: slot s holds x for the next step t with (t & 7) == s
    float xA[DIST], xB[DIST], xC[DIST];
#pragma unroll
    for (int s = 0; s < DIST; s++) {
        xA[s] = xin[(size_t)s * HP + rowA];
        xB[s] = xin[(size_t)s * HP + rowB];
        xC[s] = hasC ? xin[(size_t)s * HP + rowC] : 0.f;
    }

    const f32x4 Z = {0.f, 0.f, 0.f, 0.f};   // persistent zero C-operand (no per-step init)

// One timestep. Chains seeded via mfma(w[0],bf[0],Z) / mfma(w[5],bf[5],Z); single
// interleaved loop gives 6 independent MFMAs between dependent pairs. x consumed from
// slot, slot refilled for t+8 (latency fully hidden; vmcnt never drained in-loop).
#define STEP(t_, R_, s_) do {                                                          \
        float xvA = xA[s_], xvB = xB[s_], xvC = xC[s_];                                \
        xA[s_] = xin[(size_t)((t_) + DIST) * HP + rowA];                               \
        xB[s_] = xin[(size_t)((t_) + DIST) * HP + rowB];                               \
        if (hasC) xC[s_] = xin[(size_t)((t_) + DIST) * HP + rowC];                     \
        f16x8 bf[KC];                                                                  \
        _Pragma("unroll")                                                              \
        for (int kc = 0; kc < KC; kc++)                                                \
            bf[kc] = *(const f16x8*)&hlds[R_][kc * 32 + g * 8];                        \
        f32x4 aA0 = __builtin_amdgcn_mfma_f32_16x16x32_f16(wA[0], bf[0], Z, 0, 0, 0);  \
        f32x4 aB0 = __builtin_amdgcn_mfma_f32_16x16x32_f16(wB[0], bf[0], Z, 0, 0, 0);  \
        f32x4 aC0 = hasC ? __builtin_amdgcn_mfma_f32_16x16x32_f16(wC[0], bf[0], Z, 0, 0, 0) : Z; \
        f32x4 aA1 = __builtin_amdgcn_mfma_f32_16x16x32_f16(wA[5], bf[5], Z, 0, 0, 0);  \
        f32x4 aB1 = __builtin_amdgcn_mfma_f32_16x16x32_f16(wB[5], bf[5], Z, 0, 0, 0);  \
        f32x4 aC1 = hasC ? __builtin_amdgcn_mfma_f32_16x16x32_f16(wC[5], bf[5], Z, 0, 0, 0) : Z; \
        _Pragma("unroll")                                                              \
        for (int j = 1; j < 5; j++) {                                                  \
            aA0 = __builtin_amdgcn_mfma_f32_16x16x32_f16(wA[j], bf[j], aA0, 0, 0, 0);  \
            aB0 = __builtin_amdgcn_mfma_f32_16x16x32_f16(wB[j], bf[j], aB0, 0, 0, 0);  \
            if (hasC)                                                                  \
            aC0 = __builtin_amdgcn_mfma_f32_16x16x32_f16(wC[j], bf[j], aC0, 0, 0, 0);  \
            aA1 = __builtin_amdgcn_mfma_f32_16x16x32_f16(wA[j + 5], bf[j + 5], aA1, 0, 0, 0); \
            aB1 = __builtin_amdgcn_mfma_f32_16x16x32_f16(wB[j + 5], bf[j + 5], aB1, 0, 0, 0); \
            if (hasC)                                                                  \
            aC1 = __builtin_amdgcn_mfma_f32_16x16x32_f16(wC[j + 5], bf[j + 5], aC1, 0, 0, 0); \
        }                                                                              \
        float sA = sel4(aA0, c1, c2) + sel4(aA1, c1, c2);                              \
        float sB = sel4(aB0, c1, c2) + sel4(aB1, c1, c2);                              \
        float yA = fast_tanh(sA + xvA);                                                \
        float yB = fast_tanh(sB + xvB);                                                \
        float yC = 0.f;                                                                \
        if (hasC) {                                                                    \
            float sC = sel4(aC0, c1, c2) + sel4(aC1, c1, c2);                          \
            yC = fast_tanh(sC + xvC);                                                  \
        }                                                                              \
        if (writer) {                                                                  \
            _Float16 hA = (_Float16)yA, hB = (_Float16)yB, hC = (_Float16)yC;          \
            hlds[1 - (R_)][tA * 16 + g * 4 + col] = hA;                                \
            hlds[1 - (R_)][tB * 16 + g * 4 + col] = hB;                                \
            if (hasC) hlds[1 - (R_)][tC * 16 + g * 4 + col] = hC;                      \
            if (ROLE0) {                                                               \
                h16[(size_t)(t_) * HP + rowA] = hA;                                    \
                h16[(size_t)(t_) * HP + rowB] = hB;                                    \
                if (hasC) h16[(size_t)(t_) * HP + rowC] = hC;                          \
            } else {                                                                   \
                h32[(size_t)(t_) * HP + rowA] = yA;                                    \
                h32[(size_t)(t_) * HP + rowB] = yB;                                    \
                if (hasC) h32[(size_t)(t_) * HP + rowC] = yC;                          \
            }                                                                          \
        }                                                                              \
    } while (0)

// barrier with LDS drain; "memory" clobber orders memory ops but leaves ALU free to
// schedule into the barrier shadow (vmcnt never drained: x prefetch stays in flight)
#define BAR() asm volatile("s_waitcnt lgkmcnt(0)\n\ts_barrier" ::: "memory")

#pragma unroll 1
    for (int c = 0; c < NCHUNK; ++c) {
        if (!ROLE0 && c > 0) {
            int tgt = (c + 2) < NCHUNK ? (c + 2) : NCHUNK;
            wait_flag(&g_flag1, tgt);
        }
#pragma unroll 1
        for (int tt = 0; tt < CHUNK; tt += DIST) {
            const int tb = c * CHUNK + tt;
            STEP(tb + 0, 0, 0); BAR();
            STEP(tb + 1, 1, 1); BAR();
            STEP(tb + 2, 0, 2); BAR();
            STEP(tb + 3, 1, 3); BAR();
            STEP(tb + 4, 0, 4); BAR();
            STEP(tb + 5, 1, 5); BAR();
            STEP(tb + 6, 0, 6); BAR();
            STEP(tb + 7, 1, 7); BAR();
        }
        if (ROLE0) publish_flag(&g_flag0, c + 1);
    }
#undef STEP
#undef BAR
}

// ---------------- proj role: x1[t] = W_ih1 h0[t] + (b_ih1+b_hh1), chunked ----------------
__device__ __forceinline__ void proj_role(const float* __restrict__ Wih,
                                          const float* __restrict__ b1,
                                          const float* __restrict__ b2)
{
    const int tid  = threadIdx.x;
    const int lane = tid & 63;
    const int wave = tid >> 6;
    const int col  = lane & 15;      // timestep-within-16-group (B col / D col)
    const int g    = lane >> 4;      // k-subgroup / D row-group

    const int tA = wave, tB = wave + 8, tC = wave + 16;
    const bool hasC = (wave < 3);

    f16x8 wA[KC], wB[KC], wC[KC];
#pragma unroll
    for (int kc = 0; kc < KC; kc++) {
        wA[kc] = loadw_frag(Wih, tA, col, g, kc);
        wB[kc] = loadw_frag(Wih, tB, col, g, kc);
        if (hasC) wC[kc] = loadw_frag(Wih, tC, col, g, kc);
        else {
            f16x8 z;
#pragma unroll
            for (int j = 0; j < 8; j++) z[j] = (_Float16)0.f;
            wC[kc] = z;
        }
    }
    // bias vectors for this lane's 4 output rows per tile (zero for j>=HID)
    f32x4 bA, bB, bC;
#pragma unroll
    for (int e = 0; e < 4; e++) {
        int jA = tA * 16 + g * 4 + e, jB = tB * 16 + g * 4 + e, jC = tC * 16 + g * 4 + e;
        bA[e] = (jA < HID) ? b1[jA] + b2[jA] : 0.f;
        bB[e] = (jB < HID) ? b1[jB] + b2[jB] : 0.f;
        bC[e] = (hasC && jC < HID) ? b1[jC] + b2[jC] : 0.f;
    }

    const f32x4 zero4 = {0.f, 0.f, 0.f, 0.f};

#pragma unroll 1
    for (int c = 0; c < NCHUNK; ++c) {
        wait_flag(&g_flag0, c + 1);
        const int tbase = c * CHUNK;
#pragma unroll
        for (int tg = 0; tg < 4; ++tg) {
            const int t = tbase + tg * 16 + col;
            f16x8 bf[KC];
#pragma unroll
            for (int kc = 0; kc < KC; ++kc)
                bf[kc] = *(const f16x8*)&g_h0h[(size_t)t * HP + kc * 32 + g * 8];
            f32x4 aA = zero4, aB = zero4, aC = zero4;
#pragma unroll
            for (int kc = 0; kc < KC; ++kc) {
                aA = __builtin_amdgcn_mfma_f32_16x16x32_f16(wA[kc], bf[kc], aA, 0, 0, 0);
                aB = __builtin_amdgcn_mfma_f32_16x16x32_f16(wB[kc], bf[kc], aB, 0, 0, 0);
                if (hasC)
                aC = __builtin_amdgcn_mfma_f32_16x16x32_f16(wC[kc], bf[kc], aC, 0, 0, 0);
            }
            // D: col=lane&15 -> t, row=g*4+e -> j within tile; f32x4 store per tile
            *(f32x4*)&g_x1[(size_t)t * HP + tA * 16 + g * 4] = aA + bA;
            *(f32x4*)&g_x1[(size_t)t * HP + tB * 16 + g * 4] = aB + bB;
            if (hasC)
            *(f32x4*)&g_x1[(size_t)t * HP + tC * 16 + g * 4] = aC + bC;
        }
        publish_flag(&g_flag1, c + 1);
    }
}

// ---------------- fused pipeline: block0=scan0, block1=proj1, block2=scan1 ----------------
__global__ __launch_bounds__(512, 2) void k_pipeline(const float* __restrict__ W_hh0,
                                                     const float* __restrict__ W_ih1,
                                                     const float* __restrict__ b_ih1,
                                                     const float* __restrict__ b_hh1,
                                                     const float* __restrict__ W_hh1)
{
    __shared__ __align__(16) _Float16 hlds[2][HK];
    if (blockIdx.x == 0)
        scan_role<1>(hlds, W_hh0, g_x, g_h0h, nullptr);
    else if (blockIdx.x == 1)
        proj_role(W_ih1, b_ih1, b_hh1);
    else
        scan_role<0>(hlds, W_hh1, g_x1, nullptr, g_h1);
}

extern "C" void kernel_launch(void* const* d_in, const int* in_sizes, int n_in,
                              void* d_out, int out_size, void* d_ws, size_t ws_size,
                              hipStream_t stream)
{
    (void)in_sizes; (void)n_in; (void)d_ws; (void)ws_size; (void)out_size;
    const float* input = (const float*)d_in[0];
    const float* W_ih0 = (const float*)d_in[1];
    const float* W_hh0 = (const float*)d_in[2];
    const float* b_ih0 = (const float*)d_in[3];
    const float* b_hh0 = (const float*)d_in[4];
    const float* W_ih1 = (const float*)d_in[5];
    const float* W_hh1 = (const float*)d_in[6];
    const float* b_ih1 = (const float*)d_in[7];
    const float* b_hh1 = (const float*)d_in[8];
    const float* W_lin = (const float*)d_in[9];
    const float* b_lin = (const float*)d_in[10];
    float* out = (float*)d_out;

    k_reset<<<dim3(1), dim3(1), 0, stream>>>();
    k_transpose<<<dim3((IN_D * HP + 255) / 256), dim3(256), 0, stream>>>(W_ih0, HID, IN_D, HP, 0);
    k_transpose<<<dim3((HID * OUTP + 255) / 256), dim3(256), 0, stream>>>(W_lin, OUT_D, HID, OUTP, 2);

    // x0 = input @ W_ih0^T + (b_ih0 + b_hh0)
    k_gemm_in<<<dim3(T_LEN / 32), dim3(320), 0, stream>>>(input, b_ih0, b_hh0);

    // fused scan0 | proj1 | scan1 pipeline (3 co-resident workgroups)
    k_pipeline<<<dim3(3), dim3(512), 0, stream>>>(W_hh0, W_ih1, b_ih1, b_hh1, W_hh1);

    // head
    k_gemm_out<<<dim3(T_LEN / 64), dim3(128), 0, stream>>>(b_lin, out);
}